// Round 4
// baseline (967.080 us; speedup 1.0000x reference)
//
#include <hip/hip_runtime.h>

typedef unsigned short u16;
typedef short short8 __attribute__((ext_vector_type(8)));
typedef float floatx4 __attribute__((ext_vector_type(4)));

#define SQ 2048
#define NH 16
#define HD 128
#define RD 64
#define NB 2

__device__ __forceinline__ float bf2f(u16 u) {
  union { unsigned u; float f; } v; v.u = ((unsigned)u) << 16; return v.f;
}
__device__ __forceinline__ u16 f2bf(float f) {
  union { float f; unsigned u; } v; v.f = f;
  return (u16)((v.u + 0x7FFFu + ((v.u >> 16) & 1u)) >> 16);
}
__device__ __forceinline__ void gll16(const u16* g, u16* l) {
  __builtin_amdgcn_global_load_lds((const __attribute__((address_space(1))) void*)g,
                                   (__attribute__((address_space(3))) void*)l, 16, 0, 0);
}

// ---- dtype sniffer: flag=1 if inputs are f32, 0 if bf16 ----
__global__ void detect_dtype(const unsigned* __restrict__ x, int* __restrict__ flag) {
  __shared__ int cnt[256];
  int c = 0;
#pragma unroll
  for (int i = 0; i < 16; i++) {
    unsigned w = x[threadIdx.x * 16 + i];
    int e = (w >> 7) & 0xFF;  // exponent of LOW u16 viewed as bf16
    c += (e >= 118 && e <= 132) ? 1 : 0;
  }
  cnt[threadIdx.x] = c;
  __syncthreads();
  if (threadIdx.x == 0) {
    int s = 0;
    for (int i = 0; i < 256; i++) s += cnt[i];
    *flag = (s < 2048) ? 1 : 0;
  }
}

// ---- convert src (f32 or bf16 per flag) -> bf16 dst ----
__global__ void convert_bf16(const void* __restrict__ src, u16* __restrict__ dst,
                             int n, const int* __restrict__ flag) {
  const int isf32 = *flag;
  for (int i = blockIdx.x * 256 + threadIdx.x; i < n; i += gridDim.x * 256)
    dst[i] = isf32 ? f2bf(((const float*)src)[i]) : ((const u16*)src)[i];
}

// ---- weight transpose: in[R][C] (f32 or bf16) -> out[C][R] bf16 ----
__global__ __launch_bounds__(256) void transpose_any(const void* __restrict__ in,
                                                     u16* __restrict__ out,
                                                     int R, int C,
                                                     const int* __restrict__ flag) {
  const int isf32 = *flag;
  __shared__ u16 tile[32][33];
  const int c0 = blockIdx.x * 32, r0 = blockIdx.y * 32;
  const int x = threadIdx.x & 31, y = threadIdx.x >> 5;
#pragma unroll
  for (int i = 0; i < 32; i += 8) {
    const size_t idx = (size_t)(r0 + y + i) * C + c0 + x;
    tile[y + i][x] = isf32 ? f2bf(((const float*)in)[idx]) : ((const u16*)in)[idx];
  }
  __syncthreads();
#pragma unroll
  for (int i = 0; i < 32; i += 8)
    out[(size_t)(c0 + y + i) * R + r0 + x] = tile[x][y + i];
}

// ---- V [B,S,H,HD] -> Vt [B,H,HD,S] (bf16) ----
__global__ __launch_bounds__(256) void transpose_v(const u16* __restrict__ V,
                                                   u16* __restrict__ Vt) {
  __shared__ u16 tile[32][33];
  const int bh = blockIdx.z, b = bh >> 4, hh = bh & 15;
  const u16* pin = V + (size_t)b * SQ * NH * HD + (size_t)hh * HD;
  u16* pout = Vt + (size_t)bh * HD * SQ;
  const int s0 = blockIdx.x * 32, d0 = blockIdx.y * 32;
  const int x = threadIdx.x & 31, y = threadIdx.x >> 5;
#pragma unroll
  for (int i = 0; i < 32; i += 8)
    tile[y + i][x] = pin[(size_t)(s0 + y + i) * (NH * HD) + d0 + x];
  __syncthreads();
#pragma unroll
  for (int i = 0; i < 32; i += 8)
    pout[(size_t)(d0 + y + i) * SQ + s0 + x] = tile[x][y + i];
}

// ---- RoPE in place on [B,S,H,RD] bf16 ----
__global__ __launch_bounds__(256) void rope_inplace(u16* __restrict__ buf) {
  const int i = blockIdx.x * 256 + threadIdx.x;
  if (i >= NB * SQ * NH * 32) return;
  const int j = i & 31;
  const int s = (i >> 9) & 2047;
  const size_t off = (size_t)(i >> 5) * RD + 2 * (i & 31);
  const float x1 = bf2f(buf[off]), x2 = bf2f(buf[off + 1]);
  const float inv = exp2f(-(float)j * 0.41524101186092031f);  // 10000^(-j/32)
  const float ang = (float)s * inv;
  float sn, cs;
  sincosf(ang, &sn, &cs);
  buf[off]     = f2bf(x1 * cs - x2 * sn);
  buf[off + 1] = f2bf(x1 * sn + x2 * cs);
}

// ---- C[M,N] = A[M,K] * Bt[N,K]^T + bias (bf16 in, fp32 accum) ----
// wf32: 1 -> write float32, 0 -> write bf16
__global__ __launch_bounds__(256) void gemm_bt(const u16* __restrict__ A,
                                               const u16* __restrict__ Bt,
                                               const u16* __restrict__ bias,
                                               void* __restrict__ Cout, int wf32,
                                               int M, int N, int K) {
  __shared__ __align__(16) u16 lA[128 * 32];
  __shared__ __align__(16) u16 lB[128 * 32];
  const int t = threadIdx.x;
  const int lane = t & 63, w = t >> 6;
  const int wm = w & 1, wn = w >> 1;
  const int m0 = blockIdx.y * 128, n0 = blockIdx.x * 128;
  const int srow = t >> 2, scol = (t & 3) * 8;
  const u16* gA = A + (size_t)(m0 + srow) * K + scol;
  const u16* gB = Bt + (size_t)(n0 + srow) * K + scol;
  u16* lA0 = lA + (16 * w) * 32;
  u16* lA1 = lA + (64 + 16 * w) * 32;
  u16* lB0 = lB + (16 * w) * 32;
  u16* lB1 = lB + (64 + 16 * w) * 32;
  const int lane_m = lane & 15, lane_k = (lane >> 4) * 8;
  floatx4 acc[4][4] = {};
  for (int k0 = 0; k0 < K; k0 += 32) {
    gll16(gA + k0, lA0);
    gll16(gA + (size_t)64 * K + k0, lA1);
    gll16(gB + k0, lB0);
    gll16(gB + (size_t)64 * K + k0, lB1);
    __syncthreads();
    short8 af[4], bf[4];
#pragma unroll
    for (int i = 0; i < 4; i++)
      af[i] = *(const short8*)(lA + (wm * 64 + i * 16 + lane_m) * 32 + lane_k);
#pragma unroll
    for (int i = 0; i < 4; i++)
      bf[i] = *(const short8*)(lB + (wn * 64 + i * 16 + lane_m) * 32 + lane_k);
#pragma unroll
    for (int mi = 0; mi < 4; mi++)
#pragma unroll
      for (int ni = 0; ni < 4; ni++)
        acc[mi][ni] = __builtin_amdgcn_mfma_f32_16x16x32_bf16(af[mi], bf[ni], acc[mi][ni], 0, 0, 0);
    __syncthreads();
  }
  const int quad = lane >> 4;
#pragma unroll
  for (int ni = 0; ni < 4; ni++) {
    const int col = n0 + wn * 64 + ni * 16 + lane_m;
    const float bv = bf2f(bias[col]);
#pragma unroll
    for (int mi = 0; mi < 4; mi++) {
      const int row = m0 + wm * 64 + mi * 16 + quad * 4;
      if (wf32) {
        float* pc = (float*)Cout + (size_t)row * N + col;
#pragma unroll
        for (int r = 0; r < 4; r++)
          pc[(size_t)r * N] = acc[mi][ni][r] + bv;
      } else {
        u16* pc = (u16*)Cout + (size_t)row * N + col;
#pragma unroll
        for (int r = 0; r < 4; r++)
          pc[(size_t)r * N] = f2bf(acc[mi][ni][r] + bv);
      }
    }
  }
}

// ---- flash attention: grid (SQ/64, NB*NH), 4 waves, wave w owns 16 q-rows ----
__global__ __launch_bounds__(256) void flash_attn(const u16* __restrict__ Qc,
                                                  const u16* __restrict__ Qr,
                                                  const u16* __restrict__ Kc,
                                                  const u16* __restrict__ Kr,
                                                  const u16* __restrict__ Vt,
                                                  u16* __restrict__ Ctx) {
  __shared__ __align__(16) u16 lKc[64 * 128];
  __shared__ __align__(16) u16 lKr[64 * 64];
  __shared__ __align__(16) u16 lVt[128 * 64];
  __shared__ __align__(16) u16 lP[4 * 16 * 64];
  const int t = threadIdx.x, lane = t & 63, w = t >> 6;
  const int qt = blockIdx.x;
  const int h = blockIdx.y & (NH - 1);
  const int b = blockIdx.y >> 4;
  const int q0 = qt * 64;
  const int lane_m = lane & 15, quad = lane >> 4, lane_k = quad * 8;

  const int qrow = q0 + 16 * w + lane_m;
  const u16* qcp = Qc + ((size_t)(b * SQ + qrow) * NH + h) * HD;
  const u16* qrp = Qr + ((size_t)(b * SQ + qrow) * NH + h) * RD;
  short8 qfc[4], qfr[2];
#pragma unroll
  for (int ks = 0; ks < 4; ks++) qfc[ks] = *(const short8*)(qcp + ks * 32 + lane_k);
#pragma unroll
  for (int ks = 0; ks < 2; ks++) qfr[ks] = *(const short8*)(qrp + ks * 32 + lane_k);

  floatx4 O[8] = {};
  float mrow[4], lsum[4];
#pragma unroll
  for (int r = 0; r < 4; r++) { mrow[r] = -1e30f; lsum[r] = 0.f; }

  const u16* gKc = Kc + ((size_t)b * SQ * NH + h) * HD;  // + key*2048 + d
  const u16* gKr = Kr + ((size_t)b * SQ * NH + h) * RD;  // + key*1024 + d
  const u16* gVt = Vt + (size_t)(b * NH + h) * HD * SQ;  // + d*SQ + key
  const float scale = 0.07216878364870323f;  // 1/sqrt(192)
  const float L2E = 1.44269504088896f;

  for (int kt = 0; kt <= qt; kt++) {
    const int kb = kt * 64;
#pragma unroll
    for (int c = t; c < 1024; c += 256) {
      const int row = c >> 4, col = (c & 15) * 8;
      *(short8*)(lKc + row * 128 + col) =
          *(const short8*)(gKc + (size_t)(kb + row) * (NH * HD) + col);
    }
#pragma unroll
    for (int c = t; c < 512; c += 256) {
      const int row = c >> 3, col = (c & 7) * 8;
      *(short8*)(lKr + row * 64 + col) =
          *(const short8*)(gKr + (size_t)(kb + row) * (NH * RD) + col);
    }
#pragma unroll
    for (int c = t; c < 1024; c += 256) {
      const int row = c >> 3, col = (c & 7) * 8;
      *(short8*)(lVt + row * 64 + col) =
          *(const short8*)(gVt + (size_t)row * SQ + kb + col);
    }
    __syncthreads();

    float ss[4][4];
#pragma unroll
    for (int n = 0; n < 4; n++) {
      floatx4 a = {0.f, 0.f, 0.f, 0.f};
#pragma unroll
      for (int ks = 0; ks < 4; ks++) {
        const short8 kf = *(const short8*)(lKc + (n * 16 + lane_m) * 128 + ks * 32 + lane_k);
        a = __builtin_amdgcn_mfma_f32_16x16x32_bf16(qfc[ks], kf, a, 0, 0, 0);
      }
#pragma unroll
      for (int ks = 0; ks < 2; ks++) {
        const short8 kf = *(const short8*)(lKr + (n * 16 + lane_m) * 64 + ks * 32 + lane_k);
        a = __builtin_amdgcn_mfma_f32_16x16x32_bf16(qfr[ks], kf, a, 0, 0, 0);
      }
#pragma unroll
      for (int r = 0; r < 4; r++) ss[n][r] = a[r] * scale;
    }
    if (kt == qt) {
#pragma unroll
      for (int n = 0; n < 4; n++) {
        const int kcol = kb + n * 16 + lane_m;
#pragma unroll
        for (int r = 0; r < 4; r++) {
          const int row = q0 + 16 * w + quad * 4 + r;
          if (kcol > row) ss[n][r] = -1e30f;
        }
      }
    }
    float pw[4][4];
#pragma unroll
    for (int r = 0; r < 4; r++) {
      float m = fmaxf(fmaxf(ss[0][r], ss[1][r]), fmaxf(ss[2][r], ss[3][r]));
#pragma unroll
      for (int d = 1; d < 16; d <<= 1) m = fmaxf(m, __shfl_xor(m, d));
      const float mn = fmaxf(mrow[r], m);
      const float alpha = exp2f((mrow[r] - mn) * L2E);
      mrow[r] = mn;
      float s = 0.f;
#pragma unroll
      for (int n = 0; n < 4; n++) {
        const float p = exp2f((ss[n][r] - mn) * L2E);
        pw[n][r] = p;
        s += p;
      }
#pragma unroll
      for (int d = 1; d < 16; d <<= 1) s += __shfl_xor(s, d);
      lsum[r] = lsum[r] * alpha + s;
#pragma unroll
      for (int vb = 0; vb < 8; vb++) O[vb][r] *= alpha;
    }
#pragma unroll
    for (int n = 0; n < 4; n++)
#pragma unroll
      for (int r = 0; r < 4; r++)
        lP[w * 1024 + (quad * 4 + r) * 64 + n * 16 + lane_m] = f2bf(pw[n][r]);
    asm volatile("s_waitcnt lgkmcnt(0)" ::: "memory");
#pragma unroll
    for (int ks = 0; ks < 2; ks++) {
      const short8 pf = *(const short8*)(lP + w * 1024 + lane_m * 64 + ks * 32 + lane_k);
#pragma unroll
      for (int vb = 0; vb < 8; vb++) {
        const short8 vf = *(const short8*)(lVt + (vb * 16 + lane_m) * 64 + ks * 32 + lane_k);
        O[vb] = __builtin_amdgcn_mfma_f32_16x16x32_bf16(pf, vf, O[vb], 0, 0, 0);
      }
    }
    __syncthreads();
  }
  float inv[4];
#pragma unroll
  for (int r = 0; r < 4; r++) inv[r] = 1.f / lsum[r];
#pragma unroll
  for (int vb = 0; vb < 8; vb++) {
#pragma unroll
    for (int r = 0; r < 4; r++) {
      const int row = q0 + 16 * w + quad * 4 + r;
      Ctx[((size_t)(b * SQ + row) * NH + h) * HD + vb * 16 + lane_m] = f2bf(O[vb][r] * inv[r]);
    }
  }
}

extern "C" void kernel_launch(void* const* d_in, const int* in_sizes, int n_in,
                              void* d_out, int out_size, void* d_ws, size_t ws_size,
                              hipStream_t stream) {
  (void)in_sizes; (void)n_in; (void)out_size; (void)ws_size;
  const void* x    = d_in[0];
  const void* kvdw = d_in[2];
  const void* kvdb = d_in[3];
  const void* kuw  = d_in[4];
  const void* kub  = d_in[5];
  const void* vuw  = d_in[6];
  const void* vub  = d_in[7];
  const void* krw  = d_in[8];
  const void* krb  = d_in[9];
  const void* qdw  = d_in[10];
  const void* qdb  = d_in[11];
  const void* quw  = d_in[12];
  const void* qub  = d_in[13];
  const void* qrw  = d_in[14];
  const void* qrb  = d_in[15];
  const void* ow   = d_in[16];
  const void* ob   = d_in[17];

  u16* p = (u16*)d_ws;
  int* flag = (int*)p;            p += 512;
  u16* xc  = p;                   p += (size_t)4096 * 2048;
  u16* bc  = p;                   p += 16384;
  u16* WT  = p;                   p += (size_t)2048 * 2048;
  u16* kvq = p;                   p += (size_t)4096 * 2048;   // kv_c | q_c -> Vt
  u16* Kc  = p;                   p += (size_t)4096 * 2048;
  u16* Kr  = p;                   p += (size_t)4096 * 1024;
  u16* V   = p;                   p += (size_t)4096 * 2048;   // -> Ctx
  u16* Qc  = p;                   p += (size_t)4096 * 2048;
  u16* Qr  = p;                   p += (size_t)4096 * 1024;
  u16* kv_c = kvq;
  u16* q_c  = kvq + (size_t)4096 * 512;
  u16* Vt   = kvq;
  u16* Ctx  = V;

  u16* b_kvd = bc;          // 512
  u16* b_ku  = bc + 512;    // 2048
  u16* b_vu  = bc + 2560;   // 2048
  u16* b_kr  = bc + 4608;   // 1024
  u16* b_qd  = bc + 5632;   // 1536
  u16* b_qu  = bc + 7168;   // 2048
  u16* b_qr  = bc + 9216;   // 1024
  u16* b_o   = bc + 10240;  // 2048

  detect_dtype<<<1, 256, 0, stream>>>((const unsigned*)x, flag);

  auto CV = [&](const void* src, u16* dst, int n) {
    int g = (n + 255) / 256; if (g > 4096) g = 4096;
    convert_bf16<<<g, 256, 0, stream>>>(src, dst, n, flag);
  };
  CV(x, xc, 4096 * 2048);
  CV(kvdb, b_kvd, 512);   CV(kub, b_ku, 2048); CV(vub, b_vu, 2048);
  CV(krb, b_kr, 1024);    CV(qdb, b_qd, 1536); CV(qub, b_qu, 2048);
  CV(qrb, b_qr, 1024);    CV(ob, b_o, 2048);

  auto T = [&](const void* in, int R, int C) {
    transpose_any<<<dim3(C / 32, R / 32), 256, 0, stream>>>(in, WT, R, C, flag);
  };
  auto G = [&](const u16* A, const u16* bias, void* Cout, int wf32, int N, int K) {
    gemm_bt<<<dim3(N / 128, 4096 / 128), 256, 0, stream>>>(A, WT, bias, Cout, wf32, 4096, N, K);
  };

  T(kvdw, 2048, 512);   G(xc, b_kvd, kv_c, 0, 512, 2048);
  T(qdw, 2048, 1536);   G(xc, b_qd, q_c, 0, 1536, 2048);
  T(kuw, 512, 2048);    G(kv_c, b_ku, Kc, 0, 2048, 512);
  T(vuw, 512, 2048);    G(kv_c, b_vu, V, 0, 2048, 512);
  T(krw, 512, 1024);    G(kv_c, b_kr, Kr, 0, 1024, 512);
  T(quw, 1536, 2048);   G(q_c, b_qu, Qc, 0, 2048, 1536);
  T(qrw, 1536, 1024);   G(q_c, b_qr, Qr, 0, 1024, 1536);

  rope_inplace<<<dim3((NB * SQ * NH * 32) / 256), 256, 0, stream>>>(Kr);
  rope_inplace<<<dim3((NB * SQ * NH * 32) / 256), 256, 0, stream>>>(Qr);
  transpose_v<<<dim3(SQ / 32, HD / 32, NB * NH), 256, 0, stream>>>(V, Vt);
  flash_attn<<<dim3(SQ / 64, NB * NH), 256, 0, stream>>>(Qc, Qr, Kc, Kr, Vt, Ctx);

  T(ow, 2048, 2048);
  G(Ctx, b_o, d_out, 1, 2048, 2048);
}

// Round 5
// 612.819 us; speedup vs baseline: 1.5781x; 1.5781x over previous
//
#include <hip/hip_runtime.h>

typedef unsigned short u16;
typedef short short8 __attribute__((ext_vector_type(8)));
typedef short short4v __attribute__((ext_vector_type(4)));
typedef float floatx4 __attribute__((ext_vector_type(4)));
typedef float floatx4v __attribute__((ext_vector_type(4)));

#define SQ 2048
#define NH 16
#define HD 128
#define RD 64
#define NB 2
#define LDKV 5120
#define LDQ 3072

// padded LDS strides (odd multiples of 8 u16 = 16 B)
#define LKC 136
#define LKR 72
#define LVT 72
#define LP  72

__device__ __forceinline__ float bf2f(u16 u) {
  union { unsigned u; float f; } v; v.u = ((unsigned)u) << 16; return v.f;
}
__device__ __forceinline__ u16 f2bf(float f) {
  union { float f; unsigned u; } v; v.f = f;
  return (u16)((v.u + 0x7FFFu + ((v.u >> 16) & 1u)) >> 16);
}
__device__ __forceinline__ void gll16(const u16* g, u16* l) {
  __builtin_amdgcn_global_load_lds((const __attribute__((address_space(1))) void*)g,
                                   (__attribute__((address_space(3))) void*)l, 16, 0, 0);
}

// ---- x (f32) -> bf16, vectorized ----
__global__ __launch_bounds__(256) void convert_x(const float* __restrict__ src,
                                                 u16* __restrict__ dst, int n4) {
  const int i = blockIdx.x * 256 + threadIdx.x;
  if (i >= n4) return;
  const floatx4v v = *(const floatx4v*)(src + 4 * (size_t)i);
  short4v o;
  o.x = (short)f2bf(v.x); o.y = (short)f2bf(v.y);
  o.z = (short)f2bf(v.z); o.w = (short)f2bf(v.w);
  *(short4v*)(dst + 4 * (size_t)i) = o;
}

// ---- all 8 biases (f32) -> concatenated bf16 slots ----
__global__ __launch_bounds__(256) void convert_biases(
    const float* b0, const float* b1, const float* b2, const float* b3,
    const float* b4, const float* b5, const float* b6, const float* b7,
    u16* __restrict__ bc) {
  const int i = blockIdx.x * 256 + threadIdx.x;
  if (i >= 12288) return;
  float v;
  if      (i < 512)   v = b0[i];          // kvdb
  else if (i < 2048)  v = b1[i - 512];    // qdb
  else if (i < 4096)  v = b2[i - 2048];   // kub
  else if (i < 6144)  v = b3[i - 4096];   // vub
  else if (i < 7168)  v = b4[i - 6144];   // krb
  else if (i < 9216)  v = b5[i - 7168];   // qub
  else if (i < 10240) v = b6[i - 9216];   // qrb
  else                v = b7[i - 10240];  // ob
  bc[i] = f2bf(v);
}

// ---- weight transpose: in[R][C] f32 -> out[C][R] bf16 ----
__global__ __launch_bounds__(256) void transpose_w(const float* __restrict__ in,
                                                   u16* __restrict__ out,
                                                   int R, int C) {
  __shared__ u16 tile[32][33];
  const int c0 = blockIdx.x * 32, r0 = blockIdx.y * 32;
  const int x = threadIdx.x & 31, y = threadIdx.x >> 5;
#pragma unroll
  for (int i = 0; i < 32; i += 8)
    tile[y + i][x] = f2bf(in[(size_t)(r0 + y + i) * C + c0 + x]);
  __syncthreads();
#pragma unroll
  for (int i = 0; i < 32; i += 8)
    out[(size_t)(c0 + y + i) * R + r0 + x] = tile[x][y + i];
}

// ---- V (cols 2048..4095 of KV [4096,5120]) -> Vt [B,H,HD,S] ----
__global__ __launch_bounds__(256) void transpose_v(const u16* __restrict__ KV,
                                                   u16* __restrict__ Vt) {
  __shared__ u16 tile[32][33];
  const int bh = blockIdx.z, b = bh >> 4, hh = bh & 15;
  const u16* pin = KV + (size_t)b * SQ * LDKV + 2048 + (size_t)hh * HD;
  u16* pout = Vt + (size_t)bh * HD * SQ;
  const int s0 = blockIdx.x * 32, d0 = blockIdx.y * 32;
  const int x = threadIdx.x & 31, y = threadIdx.x >> 5;
#pragma unroll
  for (int i = 0; i < 32; i += 8)
    tile[y + i][x] = pin[(size_t)(s0 + y + i) * LDKV + d0 + x];
  __syncthreads();
#pragma unroll
  for (int i = 0; i < 32; i += 8)
    pout[(size_t)(d0 + y + i) * SQ + s0 + x] = tile[x][y + i];
}

// ---- RoPE in place on a [4096 x (16*64)] submatrix at col `coloff`, ld `ld` ----
__global__ __launch_bounds__(256) void rope_inplace(u16* __restrict__ buf,
                                                    int ld, int coloff) {
  const int i = blockIdx.x * 256 + threadIdx.x;
  if (i >= NB * SQ * NH * 32) return;
  const int j = i & 31;
  const int hh = (i >> 5) & 15;
  const int row = i >> 9;
  const int s = row & (SQ - 1);
  u16* p = buf + (size_t)row * ld + coloff + hh * RD + 2 * j;
  const float x1 = bf2f(p[0]), x2 = bf2f(p[1]);
  const float inv = exp2f(-(float)j * 0.41524101186092031f);  // 10000^(-j/32)
  const float ang = (float)s * inv;
  float sn, cs;
  sincosf(ang, &sn, &cs);
  p[0] = f2bf(x1 * cs - x2 * sn);
  p[1] = f2bf(x1 * sn + x2 * cs);
}

// ---- C[M=4096,N] = A[.,K](lda) * Bt[N,K]^T + bias; out bf16(ldc) or f32 ----
__global__ __launch_bounds__(256) void gemm_bt(const u16* __restrict__ A, int lda,
                                               const u16* __restrict__ Bt,
                                               const u16* __restrict__ bias,
                                               void* __restrict__ Cout, int ldc,
                                               int wf32, int N, int K) {
  __shared__ __align__(16) u16 lA[128 * 32];
  __shared__ __align__(16) u16 lB[128 * 32];
  const int t = threadIdx.x;
  const int lane = t & 63, w = t >> 6;
  const int wm = w & 1, wn = w >> 1;
  const int m0 = blockIdx.y * 128, n0 = blockIdx.x * 128;
  const int srow = t >> 2, scol = (t & 3) * 8;
  const u16* gA = A + (size_t)(m0 + srow) * lda + scol;
  const u16* gB = Bt + (size_t)(n0 + srow) * K + scol;
  u16* lA0 = lA + (16 * w) * 32;
  u16* lA1 = lA + (64 + 16 * w) * 32;
  u16* lB0 = lB + (16 * w) * 32;
  u16* lB1 = lB + (64 + 16 * w) * 32;
  const int lane_m = lane & 15, lane_k = (lane >> 4) * 8;
  floatx4 acc[4][4] = {};
  for (int k0 = 0; k0 < K; k0 += 32) {
    gll16(gA + k0, lA0);
    gll16(gA + (size_t)64 * lda + k0, lA1);
    gll16(gB + k0, lB0);
    gll16(gB + (size_t)64 * K + k0, lB1);
    __syncthreads();
    short8 af[4], bf[4];
#pragma unroll
    for (int i = 0; i < 4; i++)
      af[i] = *(const short8*)(lA + (wm * 64 + i * 16 + lane_m) * 32 + lane_k);
#pragma unroll
    for (int i = 0; i < 4; i++)
      bf[i] = *(const short8*)(lB + (wn * 64 + i * 16 + lane_m) * 32 + lane_k);
#pragma unroll
    for (int mi = 0; mi < 4; mi++)
#pragma unroll
      for (int ni = 0; ni < 4; ni++)
        acc[mi][ni] = __builtin_amdgcn_mfma_f32_16x16x32_bf16(af[mi], bf[ni], acc[mi][ni], 0, 0, 0);
    __syncthreads();
  }
  const int quad = lane >> 4;
#pragma unroll
  for (int ni = 0; ni < 4; ni++) {
    const int col = n0 + wn * 64 + ni * 16 + lane_m;
    const float bv = bf2f(bias[col]);
#pragma unroll
    for (int mi = 0; mi < 4; mi++) {
      const int row = m0 + wm * 64 + mi * 16 + quad * 4;
      if (wf32) {
        float* pc = (float*)Cout + (size_t)row * ldc + col;
#pragma unroll
        for (int r = 0; r < 4; r++)
          pc[(size_t)r * ldc] = acc[mi][ni][r] + bv;
      } else {
        u16* pc = (u16*)Cout + (size_t)row * ldc + col;
#pragma unroll
        for (int r = 0; r < 4; r++)
          pc[(size_t)r * ldc] = f2bf(acc[mi][ni][r] + bv);
      }
    }
  }
}

// ---- flash attention: grid (32, 32) = (qt, b*16+h); 4 waves, 16 q-rows each ----
// Register double-buffered staging + padded LDS (conflict-free fragment reads).
__global__ __launch_bounds__(256) void flash_attn(const u16* __restrict__ Q,
                                                  const u16* __restrict__ KV,
                                                  const u16* __restrict__ Vt,
                                                  u16* __restrict__ Ctx) {
  __shared__ __align__(16) u16 lKc[64 * LKC];
  __shared__ __align__(16) u16 lKr[64 * LKR];
  __shared__ __align__(16) u16 lVt[128 * LVT];
  __shared__ __align__(16) u16 lP[4 * 16 * LP];
  const int t = threadIdx.x, lane = t & 63, w = t >> 6;
  const int qt = 31 - blockIdx.x;  // heavy tiles dispatch first
  const int h = blockIdx.y & (NH - 1);
  const int b = blockIdx.y >> 4;
  const int q0 = qt * 64;
  const int lane_m = lane & 15, quad = lane >> 4, lane_k = quad * 8;

  // Q fragments (A-operand)
  const int qrow = q0 + 16 * w + lane_m;
  const u16* qcp = Q + (size_t)(b * SQ + qrow) * LDQ + h * HD;
  const u16* qrp = Q + (size_t)(b * SQ + qrow) * LDQ + 2048 + h * RD;
  short8 qfc[4], qfr[2];
#pragma unroll
  for (int ks = 0; ks < 4; ks++) qfc[ks] = *(const short8*)(qcp + ks * 32 + lane_k);
#pragma unroll
  for (int ks = 0; ks < 2; ks++) qfr[ks] = *(const short8*)(qrp + ks * 32 + lane_k);

  floatx4 O[8] = {};
  float mrow[4], lsum[4];
#pragma unroll
  for (int r = 0; r < 4; r++) { mrow[r] = -1e30f; lsum[r] = 0.f; }

  const u16* gKc = KV + (size_t)b * SQ * LDKV + h * HD;          // + key*LDKV + d
  const u16* gKr = KV + (size_t)b * SQ * LDKV + 4096 + h * RD;   // + key*LDKV + d
  const u16* gVt = Vt + (size_t)(b * NH + h) * HD * SQ;          // + d*SQ + key
  const float C2 = 0.10412825525540364f;  // (1/sqrt(192)) * log2(e)

  // staging thread->coords
  const int kcR = t >> 2,  kcC = (t & 3) * 8;   // +64 rows per i? no: c = t + i*256
  (void)kcR; (void)kcC;

  short8 rKc[4], rKr[2], rVt[4];
  auto load_tile = [&](int kb) {
#pragma unroll
    for (int i = 0; i < 4; i++) {
      const int c = t + i * 256, row = c >> 4, col = (c & 15) * 8;
      rKc[i] = *(const short8*)(gKc + (size_t)(kb + row) * LDKV + col);
    }
#pragma unroll
    for (int i = 0; i < 2; i++) {
      const int c = t + i * 256, row = c >> 3, col = (c & 7) * 8;
      rKr[i] = *(const short8*)(gKr + (size_t)(kb + row) * LDKV + col);
    }
#pragma unroll
    for (int i = 0; i < 4; i++) {
      const int c = t + i * 256, row = c >> 3, col = (c & 7) * 8;
      rVt[i] = *(const short8*)(gVt + (size_t)row * SQ + kb + col);
    }
  };

  load_tile(0);
  for (int kt = 0; kt <= qt; kt++) {
    const int kb = kt * 64;
    __syncthreads();  // previous tile's LDS reads complete
#pragma unroll
    for (int i = 0; i < 4; i++) {
      const int c = t + i * 256, row = c >> 4, col = (c & 15) * 8;
      *(short8*)(lKc + row * LKC + col) = rKc[i];
    }
#pragma unroll
    for (int i = 0; i < 2; i++) {
      const int c = t + i * 256, row = c >> 3, col = (c & 7) * 8;
      *(short8*)(lKr + row * LKR + col) = rKr[i];
    }
#pragma unroll
    for (int i = 0; i < 4; i++) {
      const int c = t + i * 256, row = c >> 3, col = (c & 7) * 8;
      *(short8*)(lVt + row * LVT + col) = rVt[i];
    }
    __syncthreads();
    if (kt < qt) load_tile(kb + 64);  // prefetch overlaps compute below

    float ss[4][4];
#pragma unroll
    for (int n = 0; n < 4; n++) {
      floatx4 a = {0.f, 0.f, 0.f, 0.f};
#pragma unroll
      for (int ks = 0; ks < 4; ks++) {
        const short8 kf = *(const short8*)(lKc + (n * 16 + lane_m) * LKC + ks * 32 + lane_k);
        a = __builtin_amdgcn_mfma_f32_16x16x32_bf16(qfc[ks], kf, a, 0, 0, 0);
      }
#pragma unroll
      for (int ks = 0; ks < 2; ks++) {
        const short8 kf = *(const short8*)(lKr + (n * 16 + lane_m) * LKR + ks * 32 + lane_k);
        a = __builtin_amdgcn_mfma_f32_16x16x32_bf16(qfr[ks], kf, a, 0, 0, 0);
      }
#pragma unroll
      for (int r = 0; r < 4; r++) ss[n][r] = a[r];
    }
    if (kt == qt) {  // causal mask on diagonal tile
#pragma unroll
      for (int n = 0; n < 4; n++) {
        const int kcol = kb + n * 16 + lane_m;
#pragma unroll
        for (int r = 0; r < 4; r++) {
          const int row = q0 + 16 * w + quad * 4 + r;
          if (kcol > row) ss[n][r] = -1e30f;
        }
      }
    }
    float pw[4][4];
#pragma unroll
    for (int r = 0; r < 4; r++) {
      float m = fmaxf(fmaxf(ss[0][r], ss[1][r]), fmaxf(ss[2][r], ss[3][r]));
#pragma unroll
      for (int d = 1; d < 16; d <<= 1) m = fmaxf(m, __shfl_xor(m, d));
      const float mn = fmaxf(mrow[r], m);
      const float alpha = exp2f((mrow[r] - mn) * C2);
      mrow[r] = mn;
      float s = 0.f;
#pragma unroll
      for (int n = 0; n < 4; n++) {
        const float p = exp2f((ss[n][r] - mn) * C2);
        pw[n][r] = p;
        s += p;
      }
#pragma unroll
      for (int d = 1; d < 16; d <<= 1) s += __shfl_xor(s, d);
      lsum[r] = lsum[r] * alpha + s;
#pragma unroll
      for (int vb = 0; vb < 8; vb++) O[vb][r] *= alpha;
    }
    // P: C-layout -> LDS (per-wave region) -> A-layout
#pragma unroll
    for (int n = 0; n < 4; n++)
#pragma unroll
      for (int r = 0; r < 4; r++)
        lP[(w * 16 + quad * 4 + r) * LP + n * 16 + lane_m] = f2bf(pw[n][r]);
    asm volatile("s_waitcnt lgkmcnt(0)" ::: "memory");
#pragma unroll
    for (int ks = 0; ks < 2; ks++) {
      const short8 pf = *(const short8*)(lP + (w * 16 + lane_m) * LP + ks * 32 + lane_k);
#pragma unroll
      for (int vb = 0; vb < 8; vb++) {
        const short8 vf = *(const short8*)(lVt + (vb * 16 + lane_m) * LVT + ks * 32 + lane_k);
        O[vb] = __builtin_amdgcn_mfma_f32_16x16x32_bf16(pf, vf, O[vb], 0, 0, 0);
      }
    }
  }
  float inv[4];
#pragma unroll
  for (int r = 0; r < 4; r++) inv[r] = 1.f / lsum[r];
#pragma unroll
  for (int vb = 0; vb < 8; vb++) {
#pragma unroll
    for (int r = 0; r < 4; r++) {
      const int row = q0 + 16 * w + quad * 4 + r;
      Ctx[(size_t)(b * SQ + row) * 2048 + h * HD + vb * 16 + lane_m] = f2bf(O[vb][r] * inv[r]);
    }
  }
}

extern "C" void kernel_launch(void* const* d_in, const int* in_sizes, int n_in,
                              void* d_out, int out_size, void* d_ws, size_t ws_size,
                              hipStream_t stream) {
  (void)in_sizes; (void)n_in; (void)out_size; (void)ws_size;
  const float* x    = (const float*)d_in[0];
  const float* kvdw = (const float*)d_in[2];
  const float* kvdb = (const float*)d_in[3];
  const float* kuw  = (const float*)d_in[4];
  const float* kub  = (const float*)d_in[5];
  const float* vuw  = (const float*)d_in[6];
  const float* vub  = (const float*)d_in[7];
  const float* krw  = (const float*)d_in[8];
  const float* krb  = (const float*)d_in[9];
  const float* qdw  = (const float*)d_in[10];
  const float* qdb  = (const float*)d_in[11];
  const float* quw  = (const float*)d_in[12];
  const float* qub  = (const float*)d_in[13];
  const float* qrw  = (const float*)d_in[14];
  const float* qrb  = (const float*)d_in[15];
  const float* ow   = (const float*)d_in[16];
  const float* ob   = (const float*)d_in[17];

  // workspace layout (u16 units), ~115 MB, lifetime-aliased
  u16* p = (u16*)d_ws;
  u16* bc   = p;  p += 16384;
  u16* WT1  = p;  p += (size_t)2048 * 2048;  // kvd^T | qd^T   [2048,2048]
  u16* WT2  = p;  p += (size_t)5120 * 512;   // ku^T|vu^T|kr^T [5120,512]
  u16* WT3  = p;  p += (size_t)3072 * 1536;  // qu^T|qr^T      [3072,1536]
  u16* Ctx  = WT1;                           // overlays WT1..WT3 (dead by flash)
  u16* WTo  = p;  p += (size_t)2048 * 2048;  // o^T            [2048,2048]
  u16* KVQd = p;  p += (size_t)4096 * 2048;  // kv_c|q_c       [4096,2048]
  u16* Vt   = KVQd;                          // overlays (dead after G3)
  u16* KV   = p;  p += (size_t)4096 * 5120;  // Kc|V|Kr        [4096,5120]
  u16* Qb   = p;  p += (size_t)4096 * 3072;  // Qc|Qr          [4096,3072]
  u16* xc   = Qb;                            // overlays Q (dead after G1)

  convert_x<<<dim3(8192), 256, 0, stream>>>(x, xc, 4096 * 2048 / 4);
  convert_biases<<<dim3(48), 256, 0, stream>>>(kvdb, qdb, kub, vub, krb, qub, qrb, ob, bc);

  auto T = [&](const float* in, u16* out, int R, int C) {
    transpose_w<<<dim3(C / 32, R / 32), 256, 0, stream>>>(in, out, R, C);
  };
  T(kvdw, WT1, 2048, 512);
  T(qdw,  WT1 + (size_t)512 * 2048, 2048, 1536);
  T(kuw,  WT2, 512, 2048);
  T(vuw,  WT2 + (size_t)2048 * 512, 512, 2048);
  T(krw,  WT2 + (size_t)4096 * 512, 512, 1024);
  T(quw,  WT3, 1536, 2048);
  T(qrw,  WT3 + (size_t)2048 * 1536, 1536, 1024);
  T(ow,   WTo, 2048, 2048);

  auto G = [&](const u16* A, int lda, const u16* Bt, const u16* bias,
               void* Cout, int ldc, int wf32, int N, int K) {
    gemm_bt<<<dim3(N / 128, 4096 / 128), 256, 0, stream>>>(A, lda, Bt, bias, Cout, ldc, wf32, N, K);
  };
  G(xc, 2048, WT1, bc, KVQd, 2048, 0, 2048, 2048);                 // kv_c | q_c
  G(KVQd, 2048, WT2, bc + 2048, KV, LDKV, 0, 5120, 512);           // Kc | V | Kr
  G(KVQd + 512, 2048, WT3, bc + 7168, Qb, LDQ, 0, 3072, 1536);     // Qc | Qr

  rope_inplace<<<dim3((NB * SQ * NH * 32) / 256), 256, 0, stream>>>(KV, LDKV, 4096);
  rope_inplace<<<dim3((NB * SQ * NH * 32) / 256), 256, 0, stream>>>(Qb, LDQ, 2048);
  transpose_v<<<dim3(SQ / 32, HD / 32, NB * NH), 256, 0, stream>>>(KV, Vt);
  flash_attn<<<dim3(32, 32), 256, 0, stream>>>(Qb, KV, Vt, Ctx);

  G(Ctx, 2048, WTo, bc + 10240, d_out, 2048, 1, 2048, 2048);       // out proj (f32)
}